// Round 1
// baseline (1044.288 us; speedup 1.0000x reference)
//
#include <hip/hip_runtime.h>
#include <hip/hip_bf16.h>
#include <math.h>

#define NP   10000
#define NEMB 20000
#define DD   128
#define NA   8192
#define EU   4096
#define ER   8192

#define WS_DINV   0
#define WS_SIMS_O 8192
#define WS_SIMS_N 16384
#define WS_ACC    24576
#define WS_M_O    32768
#define WS_M_N    65536
#define WS_S_O    98304
#define WS_S_N    131072
#define WS_CNT    163840
#define WS_HST_BYTE 786432

typedef __attribute__((ext_vector_type(8))) short short8;
typedef __attribute__((ext_vector_type(4))) float f32x4;

__device__ inline float softplusf(float x) {
  return fmaxf(x, 0.f) + log1pf(expf(-fabsf(x)));
}
__device__ inline unsigned short f32_to_bf16(float f) {
  unsigned int u = __float_as_uint(f);
  u = u + 0x7FFFu + ((u >> 16) & 1u);
  return (unsigned short)(u >> 16);
}
__device__ inline float waveReduceSum(float v) {
#pragma unroll
  for (int m = 32; m >= 1; m >>= 1) v += __shfl_xor(v, m, 64);
  return v;
}
__device__ inline void atomicMaxF(float* addr, float v) {
  if (v >= 0.f) atomicMax((int*)addr, __float_as_int(v));
  else          atomicMin((unsigned int*)addr, __float_as_uint(v));
}

__global__ __launch_bounds__(256) void k_init(float* __restrict__ ws) {
  int i = blockIdx.x * 256 + threadIdx.x;
  if (i < NEMB) {
    ws[WS_M_O + i] = -INFINITY;
    ws[WS_M_N + i] = -INFINITY;
    ws[WS_S_O + i] = 0.f;
    ws[WS_S_N + i] = 0.f;
    ws[WS_CNT + i] = 0.f;
  }
  if (i < 16) ws[WS_ACC + i] = 0.f;
}

__global__ __launch_bounds__(256) void k_lu(const float* __restrict__ pred,
                                            const int* __restrict__ ue,
                                            float* __restrict__ ws) {
  __shared__ float sacc;
  if (threadIdx.x == 0) sacc = 0.f;
  __syncthreads();
  int e = blockIdx.x * 256 + threadIdx.x;
  float v = 0.f;
  if (e < EU) {
    int u = ue[2 * e], w = ue[2 * e + 1];
    v = softplusf(pred[(long)u * NP + w]);
  }
  v = waveReduceSum(v);
  if ((threadIdx.x & 63) == 0) atomicAdd(&sacc, v);
  __syncthreads();
  if (threadIdx.x == 0) atomicAdd(ws + WS_ACC + 0, sacc);
}

__global__ __launch_bounds__(256) void k_sims(const float* __restrict__ eo,
                                              const float* __restrict__ en,
                                              const int* __restrict__ re,
                                              float* __restrict__ ws) {
  int gw = (int)((blockIdx.x * 256 + threadIdx.x) >> 6);
  int lane = threadIdx.x & 63;
  if (gw >= ER) return;
  int u = re[2 * gw], v = re[2 * gw + 1];
  const float* ou = eo + (long)u * DD;
  const float* ov = eo + (long)v * DD;
  const float* nu = en + (long)u * DD;
  const float* nv = en + (long)v * DD;
  float so = ou[lane] * ov[lane] + ou[lane + 64] * ov[lane + 64];
  float sn = nu[lane] * nv[lane] + nu[lane + 64] * nv[lane + 64];
  so = waveReduceSum(so);
  sn = waveReduceSum(sn);
  if (lane == 0) {
    ws[WS_SIMS_O + gw] = so;
    ws[WS_SIMS_N + gw] = sn;
    atomicMaxF(ws + WS_M_O + u, so);
    atomicMaxF(ws + WS_M_N + u, sn);
    atomicAdd(ws + WS_CNT + u, 1.f);
  }
}

__global__ __launch_bounds__(256) void k_ssum(const int* __restrict__ re,
                                              float* __restrict__ ws) {
  int e = blockIdx.x * 256 + threadIdx.x;
  if (e >= ER) return;
  int u = re[2 * e];
  atomicAdd(ws + WS_S_O + u, expf(ws[WS_SIMS_O + e] - ws[WS_M_O + u]));
  atomicAdd(ws + WS_S_N + u, expf(ws[WS_SIMS_N + e] - ws[WS_M_N + u]));
}

__global__ __launch_bounds__(256) void k_lp(const int* __restrict__ re,
                                            float* __restrict__ ws) {
  __shared__ float s1, s2;
  if (threadIdx.x == 0) { s1 = 0.f; s2 = 0.f; }
  __syncthreads();
  int e = blockIdx.x * 256 + threadIdx.x;
  float d2 = 0.f, mk = 0.f;
  if (e < ER) {
    int u = re[2 * e];
    float lseo = logf(ws[WS_S_O + u] + 1e-30f) + ws[WS_M_O + u];
    float lsen = logf(ws[WS_S_N + u] + 1e-30f) + ws[WS_M_N + u];
    float lpo = logf(expf(ws[WS_SIMS_O + e] - lseo) + 1e-8f);
    float lpn = logf(expf(ws[WS_SIMS_N + e] - lsen) + 1e-8f);
    mk = (ws[WS_CNT + u] > 1.f) ? 1.f : 0.f;
    float dd = lpn - lpo;
    d2 = mk * dd * dd;
  }
  d2 = waveReduceSum(d2);
  mk = waveReduceSum(mk);
  if ((threadIdx.x & 63) == 0) { atomicAdd(&s1, d2); atomicAdd(&s2, mk); }
  __syncthreads();
  if (threadIdx.x == 0) {
    atomicAdd(ws + WS_ACC + 1, s1);
    atomicAdd(ws + WS_ACC + 2, s2);
  }
}

__global__ __launch_bounds__(256) void k_deg(const float* __restrict__ A,
                                             const unsigned char* __restrict__ M,
                                             float* __restrict__ ws) {
  __shared__ float sacc;
  if (threadIdx.x == 0) sacc = 0.f;
  __syncthreads();
  long row = blockIdx.x;
  const float* a = A + row * NA;
  const unsigned char* m = M + row * NA;
  float s = 0.f;
#pragma unroll
  for (int q = 0; q < 8; ++q) {
    int c = q * 1024 + threadIdx.x * 4;
    float4 av = *(const float4*)(a + c);
    uchar4 mv = *(const uchar4*)(m + c);
    s += (mv.x ? av.x : 0.f) + (mv.y ? av.y : 0.f) +
         (mv.z ? av.z : 0.f) + (mv.w ? av.w : 0.f);
  }
  s = waveReduceSum(s);
  if ((threadIdx.x & 63) == 0) atomicAdd(&sacc, s);
  __syncthreads();
  if (threadIdx.x == 0) ws[WS_DINV + row] = 1.f / sqrtf(sacc + 1e-8f);
}

__global__ __launch_bounds__(256) void k_hst(const float* __restrict__ H,
                                             float* __restrict__ ws) {
  __shared__ float t[64][129];
  int jb = blockIdx.x * 64;
#pragma unroll
  for (int it = 0; it < 32; ++it) {
    int idx = it * 256 + threadIdx.x;
    int r = idx >> 7, c = idx & 127;
    t[r][c] = H[(long)(jb + r) * DD + c] * ws[WS_DINV + jb + r];
  }
  __syncthreads();
  unsigned short* hst = (unsigned short*)((char*)ws + WS_HST_BYTE);
#pragma unroll
  for (int it = 0; it < 32; ++it) {
    int idx = it * 256 + threadIdx.x;
    int d = idx >> 6, j = idx & 63;
    hst[(long)d * NA + jb + j] = f32_to_bf16(t[j][d]);
  }
}

__global__ __launch_bounds__(256) void k_gemm(const float* __restrict__ A,
                                              const unsigned char* __restrict__ Msk,
                                              const float* __restrict__ H,
                                              float* __restrict__ ws) {
  __shared__ __align__(16) short lsA[2][1024];
  __shared__ __align__(16) short lsB[2][8192];
  __shared__ float lsHp[16][128];
  __shared__ float wred[4];

  const char* HsT = (const char*)ws + WS_HST_BYTE;
  int tid = threadIdx.x;
  long i0 = (long)blockIdx.x * 16;

  int rowa = tid >> 4, c4a = tid & 15;
  const float* aptr = A + (i0 + rowa) * NA + 4 * c4a;
  const unsigned char* mptr = Msk + (i0 + rowa) * NA + 4 * c4a;
  int aoff = rowa * 128 + ((8 * c4a) ^ ((rowa & 7) << 4));

  int boff[4];
  const char* bptr[4];
#pragma unroll
  for (int i = 0; i < 4; ++i) {
    int chunk = i * 256 + tid;
    int rb = chunk >> 3, c16 = chunk & 7;
    boff[i] = rb * 128 + ((c16 * 16) ^ ((rb & 7) << 4));
    bptr[i] = HsT + (long)rb * (NA * 2) + c16 * 16;
  }

  float4 areg; uchar4 mreg; uint4 breg[4];

  auto LOAD = [&](int k0) {
    areg = *(const float4*)(aptr + k0);
    mreg = *(const uchar4*)(mptr + k0);
#pragma unroll
    for (int i = 0; i < 4; ++i)
      breg[i] = *(const uint4*)(bptr[i] + (long)k0 * 2);
  };
  auto STORE = [&](int buf) {
    unsigned int p0 = (unsigned int)f32_to_bf16(mreg.x ? areg.x : 0.f)
                    | ((unsigned int)f32_to_bf16(mreg.y ? areg.y : 0.f) << 16);
    unsigned int p1 = (unsigned int)f32_to_bf16(mreg.z ? areg.z : 0.f)
                    | ((unsigned int)f32_to_bf16(mreg.w ? areg.w : 0.f) << 16);
    uint2 pv; pv.x = p0; pv.y = p1;
    *(uint2*)((char*)&lsA[buf][0] + aoff) = pv;
#pragma unroll
    for (int i = 0; i < 4; ++i)
      *(uint4*)((char*)&lsB[buf][0] + boff[i]) = breg[i];
  };

  LOAD(0);
  STORE(0);

  int w = tid >> 6, lane = tid & 63, lrow = lane & 15, lgrp = lane >> 4;
  int aro[2], bro[2][2];
#pragma unroll
  for (int s = 0; s < 2; ++s) {
    aro[s] = lrow * 128 + ((64 * s + 16 * lgrp) ^ ((lrow & 7) << 4));
#pragma unroll
    for (int fl = 0; fl < 2; ++fl) {
      int brow = w * 32 + fl * 16 + lrow;
      bro[s][fl] = brow * 128 + ((64 * s + 16 * lgrp) ^ ((brow & 7) << 4));
    }
  }

  f32x4 acc0 = {0.f, 0.f, 0.f, 0.f};
  f32x4 acc1 = {0.f, 0.f, 0.f, 0.f};

  for (int t = 0; t < 128; ++t) {
    int cur = t & 1;
    if (t < 127) LOAD((t + 1) * 64);
    __syncthreads();
    const char* ab = (const char*)&lsA[cur][0];
    const char* bb = (const char*)&lsB[cur][0];
#pragma unroll
    for (int s = 0; s < 2; ++s) {
      short8 af = *(const short8*)(ab + aro[s]);
      short8 b0 = *(const short8*)(bb + bro[s][0]);
      short8 b1 = *(const short8*)(bb + bro[s][1]);
      acc0 = __builtin_amdgcn_mfma_f32_16x16x32_bf16(af, b0, acc0, 0, 0, 0);
      acc1 = __builtin_amdgcn_mfma_f32_16x16x32_bf16(af, b1, acc1, 0, 0, 0);
    }
    if (t < 127) {
      __syncthreads();
      STORE(cur ^ 1);
    }
  }

#pragma unroll
  for (int r = 0; r < 4; ++r) {
    lsHp[lgrp * 4 + r][w * 32 + lrow]      = acc0[r];
    lsHp[lgrp * 4 + r][w * 32 + 16 + lrow] = acc1[r];
  }
  __syncthreads();
  float wsum = 0.f;
#pragma unroll
  for (int r = 0; r < 4; ++r) {
    int rr = w * 4 + r;
    float hp0 = lsHp[rr][lane];
    float hp1 = lsHp[rr][lane + 64];
    float h0 = H[(i0 + rr) * DD + lane];
    float h1 = H[(i0 + rr) * DD + 64 + lane];
    float pn = h0 * hp0 + h1 * hp1;
    float pd = hp0 * hp0 + hp1 * hp1;
    float ph = h0 * h0 + h1 * h1;
    pn = waveReduceSum(pn);
    pd = waveReduceSum(pd);
    ph = waveReduceSum(ph);
    if (lane == 0) {
      float den = fmaxf(sqrtf(pd * ph), 1e-8f);
      wsum += softplusf(-(pn / den));
    }
  }
  if (lane == 0) wred[w] = wsum;
  __syncthreads();
  if (tid == 0)
    atomicAdd(ws + WS_ACC + 3, wred[0] + wred[1] + wred[2] + wred[3]);
}

__global__ void k_final(const float* __restrict__ ws, float* __restrict__ out) {
  if (threadIdx.x == 0 && blockIdx.x == 0) {
    float Lu = ws[WS_ACC + 0] / (float)EU;
    float Lp = ws[WS_ACC + 1] / fmaxf(ws[WS_ACC + 2], 1.f);
    float Lc = ws[WS_ACC + 3] / (float)NA;
    out[0] = Lu + Lp + 0.01f * Lc;
    out[1] = Lu;
    out[2] = Lp;
    out[3] = Lc;
  }
}

extern "C" void kernel_launch(void* const* d_in, const int* in_sizes, int n_in,
                              void* d_out, int out_size, void* d_ws, size_t ws_size,
                              hipStream_t stream) {
  const float* pred = (const float*)d_in[0];
  const float* eo   = (const float*)d_in[1];
  const float* en   = (const float*)d_in[2];
  const float* A    = (const float*)d_in[3];
  const float* H    = (const float*)d_in[4];
  const int*   ue   = (const int*)d_in[5];
  const int*   re   = (const int*)d_in[6];
  const unsigned char* msk = (const unsigned char*)d_in[7];
  float* ws  = (float*)d_ws;
  float* out = (float*)d_out;

  hipLaunchKernelGGL(k_init, dim3((NEMB + 255) / 256), dim3(256), 0, stream, ws);
  hipLaunchKernelGGL(k_lu,   dim3(EU / 256),  dim3(256), 0, stream, pred, ue, ws);
  hipLaunchKernelGGL(k_sims, dim3(ER / 4),    dim3(256), 0, stream, eo, en, re, ws);
  hipLaunchKernelGGL(k_ssum, dim3(ER / 256),  dim3(256), 0, stream, re, ws);
  hipLaunchKernelGGL(k_lp,   dim3(ER / 256),  dim3(256), 0, stream, re, ws);
  hipLaunchKernelGGL(k_deg,  dim3(NA),        dim3(256), 0, stream, A, msk, ws);
  hipLaunchKernelGGL(k_hst,  dim3(NA / 64),   dim3(256), 0, stream, H, ws);
  hipLaunchKernelGGL(k_gemm, dim3(NA / 16),   dim3(256), 0, stream, A, msk, H, ws);
  hipLaunchKernelGGL(k_final, dim3(1), dim3(64), 0, stream, ws, out);
}